// Round 17
// baseline (57.086 us; speedup 1.0000x reference)
//
#include <hip/hip_runtime.h>

#define BSES 64
#define EDIM 128
#define HDIM 128
#define KSCALE 2.8853900817779268f  // 2*log2(e): exp(2x) = exp2(KSCALE*x)

__device__ __forceinline__ float fexp2(float x) {
#if __has_builtin(__builtin_amdgcn_exp2f)
  return __builtin_amdgcn_exp2f(x);
#else
  return exp2f(x);
#endif
}
__device__ __forceinline__ float frcp(float x) {
#if __has_builtin(__builtin_amdgcn_rcpf)
  return __builtin_amdgcn_rcpf(x);
#else
  return 1.0f / x;
#endif
}

// 4-way batched reciprocal sum: w0/x0 + w1/x1 + w2/x2 + w3/x3,
// x_j = fma(s_j, v_j, 1). 13 VALU + 1 rcp per 4 elements. (Proven R3+.)
__device__ __forceinline__ float g4(float s0, float s1, float s2, float s3,
                                    float w0, float w1, float w2, float w3,
                                    float4 v, float acc) {
  float x0 = fmaf(s0, v.x, 1.f);
  float x1 = fmaf(s1, v.y, 1.f);
  float x2 = fmaf(s2, v.z, 1.f);
  float x3 = fmaf(s3, v.w, 1.f);
  float p01 = x0 * x1, p23 = x2 * x3;
  float n01 = fmaf(w1, x0, w0 * x1);
  float n23 = fmaf(w3, x2, w2 * x3);
  float num = fmaf(n23, p01, n01 * p23);
  return fmaf(num, frcp(p01 * p23), acc);
}

// Fused projections (R12-proven tp part VERBATIM; esp stored NATURAL [b][h]).
__global__ __launch_bounds__(256) void taa_k1(
    const float* __restrict__ sess, const float* __restrict__ W1,
    const float* __restrict__ b1, const float* __restrict__ emb,
    const float* __restrict__ W2, const float* __restrict__ b2,
    const float* __restrict__ W3, const float* __restrict__ b3,
    float* __restrict__ etp, float* __restrict__ esp,
    float* __restrict__ C_out, int N, int nbTP) {
  if ((int)blockIdx.x < nbTP) {
    __shared__ float sm[32][132];  // emb tile, padded stride
    const int nb = blockIdx.x * 32;
    for (int k = threadIdx.x; k < 32 * 32; k += 256) {
      int r = k >> 5, c4 = k & 31;
      float4 v = make_float4(0.f, 0.f, 0.f, 0.f);
      if (nb + r < N) v = ((const float4*)(emb + (size_t)(nb + r) * EDIM))[c4];
      *(float4*)&sm[r][c4 * 4] = v;
    }
    __syncthreads();
    const int h4 = (threadIdx.x & 31) * 4;
    const int rg = threadIdx.x >> 5;  // 8 groups of 4 rows
    float acc[4][4];
#pragma unroll
    for (int j = 0; j < 4; ++j)
#pragma unroll
      for (int q = 0; q < 4; ++q) acc[j][q] = 0.f;
    for (int e = 0; e < EDIM; e += 4) {
      float4 w[4];
#pragma unroll
      for (int q = 0; q < 4; ++q)
        w[q] = *(const float4*)(W2 + (size_t)(e + q) * HDIM + h4);
#pragma unroll
      for (int j = 0; j < 4; ++j) {
        float4 em = *(const float4*)&sm[rg * 4 + j][e];
        acc[j][0] = fmaf(em.x, w[0].x, acc[j][0]);
        acc[j][1] = fmaf(em.x, w[0].y, acc[j][1]);
        acc[j][2] = fmaf(em.x, w[0].z, acc[j][2]);
        acc[j][3] = fmaf(em.x, w[0].w, acc[j][3]);
        acc[j][0] = fmaf(em.y, w[1].x, acc[j][0]);
        acc[j][1] = fmaf(em.y, w[1].y, acc[j][1]);
        acc[j][2] = fmaf(em.y, w[1].z, acc[j][2]);
        acc[j][3] = fmaf(em.y, w[1].w, acc[j][3]);
        acc[j][0] = fmaf(em.z, w[2].x, acc[j][0]);
        acc[j][1] = fmaf(em.z, w[2].y, acc[j][1]);
        acc[j][2] = fmaf(em.z, w[2].z, acc[j][2]);
        acc[j][3] = fmaf(em.z, w[2].w, acc[j][3]);
        acc[j][0] = fmaf(em.w, w[3].x, acc[j][0]);
        acc[j][1] = fmaf(em.w, w[3].y, acc[j][1]);
        acc[j][2] = fmaf(em.w, w[3].z, acc[j][2]);
        acc[j][3] = fmaf(em.w, w[3].w, acc[j][3]);
      }
    }
    float4 bb2 = *(const float4*)(b2 + h4);
#pragma unroll
    for (int j = 0; j < 4; ++j) {
      int n = nb + rg * 4 + j;
      if (n < N) {
        float4 o;
        o.x = fexp2((acc[j][0] + bb2.x) * KSCALE);
        o.y = fexp2((acc[j][1] + bb2.y) * KSCALE);
        o.z = fexp2((acc[j][2] + bb2.z) * KSCALE);
        o.w = fexp2((acc[j][3] + bb2.w) * KSCALE);
        *(float4*)(etp + (size_t)n * HDIM + h4) = o;
      }
    }
  } else {
    int t = ((int)blockIdx.x - nbTP) * 256 + threadIdx.x;
    if (t < BSES * HDIM) {
      int b = t >> 7, h = t & 127;
      const float* srow = sess + b * EDIM;
      float acc = 0.f;
#pragma unroll 4
      for (int e = 0; e < EDIM; ++e)
        acc = fmaf(srow[e], W1[e * HDIM + h], acc);
      esp[t] = fexp2((acc + b1[h]) * KSCALE);  // natural [b][h]
    }
    if (t == 0) {
      float s = b3[0];
      for (int i = 0; i < HDIM; ++i) s += W3[i];
      *C_out = s;
    }
  }
}

// Scoring, ZERO-LDS: lane&31 = target, lane>>5 = h-half, wave = 8 sessions.
// Per 16-h chunk: etp in regs (per-lane VMEM, reused x8 sessions), w3
// broadcast (2-line), esp uniform-addr broadcast VMEM (L1-hot 32 KB).
// All accumulators are NAMED scalars (static indexing). h-halves folded by
// one shfl_xor(32); lanes<32 store 8 coalesced dwords.
// score[b][n] = C - 2 * sum_h w3[h] * rcp(fma(esp[b][h], etp[n][h], 1))
__global__ __launch_bounds__(256) void taa_k2(
    const float* __restrict__ etp, const float* __restrict__ esp,
    const float* __restrict__ w3, const float* __restrict__ Cptr,
    float* __restrict__ out, int N) {
  const int tid = threadIdx.x;
  const int lane = tid & 63;
  const int tl = lane & 31;                      // target within 32-tile
  const int hh = lane >> 5;                      // h-half (0/1)
  const int tile = blockIdx.x >> 1;              // 625 tiles
  const int sg = ((blockIdx.x & 1) << 2) | (tid >> 6);  // 0..7
  const int s0 = sg * 8;
  const int n = tile * 32 + tl;                  // < 20000 (625*32 exact)
  const int hbase = hh * 64;

  float a0 = 0.f, a1 = 0.f, a2 = 0.f, a3 = 0.f;
  float a4 = 0.f, a5 = 0.f, a6 = 0.f, a7 = 0.f;

#pragma unroll 1
  for (int c = 0; c < 4; ++c) {
    const int h0 = hbase + (c << 4);
    const float4* tp = (const float4*)(etp + (size_t)n * HDIM + h0);
    float4 t0 = tp[0], t1 = tp[1], t2 = tp[2], t3 = tp[3];  // per-lane regs
    const float4* wp = (const float4*)(w3 + h0);            // 2-line bcast
    float4 w0 = wp[0], w1 = wp[1], w2 = wp[2], w3v = wp[3];
#define SESS(s, A)                                                          \
    {                                                                       \
      const float4* ep = (const float4*)(esp + (size_t)(s0 + (s)) * HDIM + h0); \
      float4 e0 = ep[0], e1 = ep[1], e2 = ep[2], e3 = ep[3];                \
      A = g4(e0.x, e0.y, e0.z, e0.w, w0.x, w0.y, w0.z, w0.w, t0, A);        \
      A = g4(e1.x, e1.y, e1.z, e1.w, w1.x, w1.y, w1.z, w1.w, t1, A);        \
      A = g4(e2.x, e2.y, e2.z, e2.w, w2.x, w2.y, w2.z, w2.w, t2, A);        \
      A = g4(e3.x, e3.y, e3.z, e3.w, w3v.x, w3v.y, w3v.z, w3v.w, t3, A);    \
    }
    SESS(0, a0)
    SESS(1, a1)
    SESS(2, a2)
    SESS(3, a3)
    SESS(4, a4)
    SESS(5, a5)
    SESS(6, a6)
    SESS(7, a7)
#undef SESS
  }

  // Fold h-halves (lane ^ 32).
  a0 += __shfl_xor(a0, 32);
  a1 += __shfl_xor(a1, 32);
  a2 += __shfl_xor(a2, 32);
  a3 += __shfl_xor(a3, 32);
  a4 += __shfl_xor(a4, 32);
  a5 += __shfl_xor(a5, 32);
  a6 += __shfl_xor(a6, 32);
  a7 += __shfl_xor(a7, 32);

  const float Cv = *Cptr;  // uniform
  if (hh == 0 && n < N) {
    out[(size_t)(s0 + 0) * N + n] = fmaf(-2.f, a0, Cv);
    out[(size_t)(s0 + 1) * N + n] = fmaf(-2.f, a1, Cv);
    out[(size_t)(s0 + 2) * N + n] = fmaf(-2.f, a2, Cv);
    out[(size_t)(s0 + 3) * N + n] = fmaf(-2.f, a3, Cv);
    out[(size_t)(s0 + 4) * N + n] = fmaf(-2.f, a4, Cv);
    out[(size_t)(s0 + 5) * N + n] = fmaf(-2.f, a5, Cv);
    out[(size_t)(s0 + 6) * N + n] = fmaf(-2.f, a6, Cv);
    out[(size_t)(s0 + 7) * N + n] = fmaf(-2.f, a7, Cv);
  }
}

extern "C" void kernel_launch(void* const* d_in, const int* in_sizes, int n_in,
                              void* d_out, int out_size, void* d_ws, size_t ws_size,
                              hipStream_t stream) {
  const float* sess = (const float*)d_in[0];
  const float* emb  = (const float*)d_in[1];
  const float* W1   = (const float*)d_in[2];
  const float* b1   = (const float*)d_in[3];
  const float* W2   = (const float*)d_in[4];
  const float* b2   = (const float*)d_in[5];
  const float* W3   = (const float*)d_in[6];
  const float* b3   = (const float*)d_in[7];
  float* out = (float*)d_out;
  const int B = in_sizes[0] / EDIM;   // 64
  const int N = in_sizes[1] / EDIM;   // 20000

  float* etp = (float*)d_ws;                      // N*128 floats
  float* esp = etp + (size_t)N * HDIM;            // B*128 floats (natural)
  float* Cp  = esp + (size_t)BSES * HDIM;         // 1 float

  const int nbTP = (N + 31) / 32;                 // 625
  const int nbSP = (B * HDIM + 255) / 256;        // 32
  taa_k1<<<nbTP + nbSP, 256, 0, stream>>>(sess, W1, b1, emb, W2, b2, W3, b3,
                                          etp, esp, Cp, N, nbTP);
  const int tiles = (N + 31) / 32;                // 625
  taa_k2<<<tiles * 2, 256, 0, stream>>>(etp, esp, W3, Cp, out, N);
}

// Round 18
// 53.518 us; speedup vs baseline: 1.0667x; 1.0667x over previous
//
#include <hip/hip_runtime.h>

#define BSES 64
#define EDIM 128
#define HDIM 128
#define KSCALE 2.8853900817779268f  // 2*log2(e): exp(2x) = exp2(KSCALE*x)

__device__ __forceinline__ float fexp2(float x) {
#if __has_builtin(__builtin_amdgcn_exp2f)
  return __builtin_amdgcn_exp2f(x);
#else
  return exp2f(x);
#endif
}
__device__ __forceinline__ float frcp(float x) {
#if __has_builtin(__builtin_amdgcn_rcpf)
  return __builtin_amdgcn_rcpf(x);
#else
  return 1.0f / x;
#endif
}

// 4-way batched reciprocal sum: w0/x0 + w1/x1 + w2/x2 + w3/x3,
// x_j = fma(s_j, v_j, 1). 13 VALU + 1 rcp per 4 elements. (Proven R3+.)
__device__ __forceinline__ float g4(float s0, float s1, float s2, float s3,
                                    float w0, float w1, float w2, float w3,
                                    float4 v, float acc) {
  float x0 = fmaf(s0, v.x, 1.f);
  float x1 = fmaf(s1, v.y, 1.f);
  float x2 = fmaf(s2, v.z, 1.f);
  float x3 = fmaf(s3, v.w, 1.f);
  float p01 = x0 * x1, p23 = x2 * x3;
  float n01 = fmaf(w1, x0, w0 * x1);
  float n23 = fmaf(w3, x2, w2 * x3);
  float num = fmaf(n23, p01, n01 * p23);
  return fmaf(num, frcp(p01 * p23), acc);
}

// Fused projections (R8-proven shape). Blocks [0,nbTP): tp-projection,
// 32 targets each, output TRANSPOSED-PACKED etpT4[hq][n][4] (plane stride
// N). Blocks [nbTP,..): esp[b][h] natural; plus C = sum(W3)+b3.
__global__ __launch_bounds__(256) void taa_k1(
    const float* __restrict__ sess, const float* __restrict__ W1,
    const float* __restrict__ b1, const float* __restrict__ emb,
    const float* __restrict__ W2, const float* __restrict__ b2,
    const float* __restrict__ W3, const float* __restrict__ b3,
    float* __restrict__ etpT4, float* __restrict__ esp,
    float* __restrict__ C_out, int N, int nbTP) {
  if ((int)blockIdx.x < nbTP) {
    __shared__ float sm[32][132];  // emb tile, padded stride
    const int nb = blockIdx.x * 32;
    for (int k = threadIdx.x; k < 32 * 32; k += 256) {
      int r = k >> 5, c4 = k & 31;
      float4 v = make_float4(0.f, 0.f, 0.f, 0.f);
      if (nb + r < N) v = ((const float4*)(emb + (size_t)(nb + r) * EDIM))[c4];
      *(float4*)&sm[r][c4 * 4] = v;
    }
    __syncthreads();
    const int hq = threadIdx.x & 31;  // h-quad index = output plane
    const int h4 = hq * 4;
    const int rg = threadIdx.x >> 5;  // 8 groups of 4 rows
    float acc[4][4];
#pragma unroll
    for (int j = 0; j < 4; ++j)
#pragma unroll
      for (int q = 0; q < 4; ++q) acc[j][q] = 0.f;
    for (int e = 0; e < EDIM; e += 4) {
      float4 w[4];
#pragma unroll
      for (int q = 0; q < 4; ++q)
        w[q] = *(const float4*)(W2 + (size_t)(e + q) * HDIM + h4);
#pragma unroll
      for (int j = 0; j < 4; ++j) {
        float4 em = *(const float4*)&sm[rg * 4 + j][e];
        acc[j][0] = fmaf(em.x, w[0].x, acc[j][0]);
        acc[j][1] = fmaf(em.x, w[0].y, acc[j][1]);
        acc[j][2] = fmaf(em.x, w[0].z, acc[j][2]);
        acc[j][3] = fmaf(em.x, w[0].w, acc[j][3]);
        acc[j][0] = fmaf(em.y, w[1].x, acc[j][0]);
        acc[j][1] = fmaf(em.y, w[1].y, acc[j][1]);
        acc[j][2] = fmaf(em.y, w[1].z, acc[j][2]);
        acc[j][3] = fmaf(em.y, w[1].w, acc[j][3]);
        acc[j][0] = fmaf(em.z, w[2].x, acc[j][0]);
        acc[j][1] = fmaf(em.z, w[2].y, acc[j][1]);
        acc[j][2] = fmaf(em.z, w[2].z, acc[j][2]);
        acc[j][3] = fmaf(em.z, w[2].w, acc[j][3]);
        acc[j][0] = fmaf(em.w, w[3].x, acc[j][0]);
        acc[j][1] = fmaf(em.w, w[3].y, acc[j][1]);
        acc[j][2] = fmaf(em.w, w[3].z, acc[j][2]);
        acc[j][3] = fmaf(em.w, w[3].w, acc[j][3]);
      }
    }
    float4 bb2 = *(const float4*)(b2 + h4);
#pragma unroll
    for (int j = 0; j < 4; ++j) {
      int n = nb + rg * 4 + j;
      if (n < N) {
        float4 o;
        o.x = fexp2((acc[j][0] + bb2.x) * KSCALE);
        o.y = fexp2((acc[j][1] + bb2.y) * KSCALE);
        o.z = fexp2((acc[j][2] + bb2.z) * KSCALE);
        o.w = fexp2((acc[j][3] + bb2.w) * KSCALE);
        *(float4*)(etpT4 + ((size_t)hq * N + n) * 4) = o;
      }
    }
  } else {
    int t = ((int)blockIdx.x - nbTP) * 256 + threadIdx.x;
    if (t < BSES * HDIM) {
      int b = t >> 7, h = t & 127;
      const float* srow = sess + b * EDIM;
      float acc = 0.f;
#pragma unroll 4
      for (int e = 0; e < EDIM; ++e)
        acc = fmaf(srow[e], W1[e * HDIM + h], acc);
      esp[t] = fexp2((acc + b1[h]) * KSCALE);  // natural [b][h]
    }
    if (t == 0) {
      float s = b3[0];
      for (int i = 0; i < HDIM; ++i) s += W3[i];
      *C_out = s;
    }
  }
}

// Scoring, ZERO-LDS + coalesced etp + esp lookahead pipeline.
// lane&31 = target in 32-tile, lane>>5 = h-half. Wave = 8 sessions.
// Per 16-h chunk: 4 coalesced per-lane etpT4 dwordx4 -> regs (reused x8
// sessions); w3 2-line broadcast; esp 2-line broadcasts with 1-session
// lookahead (named eA/eB rotation) so loads overlap the 4-g4 compute.
// h-halves folded by one shfl_xor(32); lanes<32 store coalesced dwords.
// score[b][n] = C - 2 * sum_h w3[h] * rcp(fma(esp[b][h], etp[n][h], 1))
__global__ __launch_bounds__(256) void taa_k2(
    const float* __restrict__ etpT4, const float* __restrict__ esp,
    const float* __restrict__ w3, const float* __restrict__ Cptr,
    float* __restrict__ out, int N) {
  const int tid = threadIdx.x;
  const int lane = tid & 63;
  const int tl = lane & 31;                       // target within tile
  const int hh = lane >> 5;                       // h-half (0/1)
  const int tile = blockIdx.x >> 1;               // 625 tiles
  const int s0 = ((blockIdx.x & 1) << 5) | ((tid >> 6) << 3);  // 0,8,..,56
  const int n = tile * 32 + tl;                   // exact (625*32 = 20000)
  const int hq0 = hh << 4;                        // first h-quad of my half

  float a0 = 0.f, a1 = 0.f, a2 = 0.f, a3 = 0.f;
  float a4 = 0.f, a5 = 0.f, a6 = 0.f, a7 = 0.f;

#pragma unroll 1
  for (int c = 0; c < 4; ++c) {
    const int hq = hq0 + (c << 2);
    const int h0 = hq << 2;  // = hh*64 + c*16
    // etp: 4 per-lane coalesced dwordx4 (each lane its own target row part).
    float4 t0 = *(const float4*)(etpT4 + ((size_t)(hq + 0) * N + n) * 4);
    float4 t1 = *(const float4*)(etpT4 + ((size_t)(hq + 1) * N + n) * 4);
    float4 t2 = *(const float4*)(etpT4 + ((size_t)(hq + 2) * N + n) * 4);
    float4 t3 = *(const float4*)(etpT4 + ((size_t)(hq + 3) * N + n) * 4);
    // w3: 2-line broadcast.
    const float4* wp = (const float4*)(w3 + h0);
    float4 w0 = wp[0], w1 = wp[1], w2 = wp[2], w3v = wp[3];
    // esp pipeline: load session s+1 while computing session s.
    const float* eb = esp + (size_t)s0 * HDIM + h0;
    float4 eA0, eA1, eA2, eA3, eB0, eB1, eB2, eB3;
    eA0 = ((const float4*)eb)[0];
    eA1 = ((const float4*)eb)[1];
    eA2 = ((const float4*)eb)[2];
    eA3 = ((const float4*)eb)[3];
#define STEP(s, A, HASNEXT)                                                 \
    {                                                                       \
      if (HASNEXT) {                                                        \
        const float4* ep_ = (const float4*)(eb + ((s) + 1) * HDIM);         \
        eB0 = ep_[0]; eB1 = ep_[1]; eB2 = ep_[2]; eB3 = ep_[3];             \
      }                                                                     \
      A = g4(eA0.x, eA0.y, eA0.z, eA0.w, w0.x, w0.y, w0.z, w0.w, t0, A);    \
      A = g4(eA1.x, eA1.y, eA1.z, eA1.w, w1.x, w1.y, w1.z, w1.w, t1, A);    \
      A = g4(eA2.x, eA2.y, eA2.z, eA2.w, w2.x, w2.y, w2.z, w2.w, t2, A);    \
      A = g4(eA3.x, eA3.y, eA3.z, eA3.w, w3v.x, w3v.y, w3v.z, w3v.w, t3, A);\
      eA0 = eB0; eA1 = eB1; eA2 = eB2; eA3 = eB3;                           \
    }
    STEP(0, a0, 1)
    STEP(1, a1, 1)
    STEP(2, a2, 1)
    STEP(3, a3, 1)
    STEP(4, a4, 1)
    STEP(5, a5, 1)
    STEP(6, a6, 1)
    STEP(7, a7, 0)
#undef STEP
  }

  // Fold h-halves (lane ^ 32).
  a0 += __shfl_xor(a0, 32);
  a1 += __shfl_xor(a1, 32);
  a2 += __shfl_xor(a2, 32);
  a3 += __shfl_xor(a3, 32);
  a4 += __shfl_xor(a4, 32);
  a5 += __shfl_xor(a5, 32);
  a6 += __shfl_xor(a6, 32);
  a7 += __shfl_xor(a7, 32);

  const float Cv = *Cptr;  // uniform
  if (hh == 0) {
    out[(size_t)(s0 + 0) * N + n] = fmaf(-2.f, a0, Cv);
    out[(size_t)(s0 + 1) * N + n] = fmaf(-2.f, a1, Cv);
    out[(size_t)(s0 + 2) * N + n] = fmaf(-2.f, a2, Cv);
    out[(size_t)(s0 + 3) * N + n] = fmaf(-2.f, a3, Cv);
    out[(size_t)(s0 + 4) * N + n] = fmaf(-2.f, a4, Cv);
    out[(size_t)(s0 + 5) * N + n] = fmaf(-2.f, a5, Cv);
    out[(size_t)(s0 + 6) * N + n] = fmaf(-2.f, a6, Cv);
    out[(size_t)(s0 + 7) * N + n] = fmaf(-2.f, a7, Cv);
  }
}

extern "C" void kernel_launch(void* const* d_in, const int* in_sizes, int n_in,
                              void* d_out, int out_size, void* d_ws, size_t ws_size,
                              hipStream_t stream) {
  const float* sess = (const float*)d_in[0];
  const float* emb  = (const float*)d_in[1];
  const float* W1   = (const float*)d_in[2];
  const float* b1   = (const float*)d_in[3];
  const float* W2   = (const float*)d_in[4];
  const float* b2   = (const float*)d_in[5];
  const float* W3   = (const float*)d_in[6];
  const float* b3   = (const float*)d_in[7];
  float* out = (float*)d_out;
  const int B = in_sizes[0] / EDIM;   // 64
  const int N = in_sizes[1] / EDIM;   // 20000

  float* etpT4 = (float*)d_ws;                    // 128*N floats (transposed)
  float* esp   = etpT4 + (size_t)HDIM * N;        // B*128 floats (natural)
  float* Cp    = esp + (size_t)BSES * HDIM;       // 1 float

  const int nbTP = (N + 31) / 32;                 // 625
  const int nbSP = (B * HDIM + 255) / 256;        // 32
  taa_k1<<<nbTP + nbSP, 256, 0, stream>>>(sess, W1, b1, emb, W2, b2, W3, b3,
                                          etpT4, esp, Cp, N, nbTP);
  const int tiles = (N + 31) / 32;                // 625
  taa_k2<<<tiles * 2, 256, 0, stream>>>(etpT4, esp, W3, Cp, out, N);
}

// Round 20
// 42.984 us; speedup vs baseline: 1.3281x; 1.2451x over previous
//
#include <hip/hip_runtime.h>

#define BSES 64
#define EDIM 128
#define HDIM 128
#define KSCALE 2.8853900817779268f  // 2*log2(e): exp(2x) = exp2(KSCALE*x)

typedef float v2f __attribute__((ext_vector_type(2)));

__device__ __forceinline__ float fexp2(float x) {
#if __has_builtin(__builtin_amdgcn_exp2f)
  return __builtin_amdgcn_exp2f(x);
#else
  return exp2f(x);
#endif
}
__device__ __forceinline__ float frcp(float x) {
#if __has_builtin(__builtin_amdgcn_rcpf)
  return __builtin_amdgcn_rcpf(x);
#else
  return 1.0f / x;
#endif
}
__device__ __forceinline__ v2f mkv2(float a, float b) {
  v2f r;
  r.x = a;
  r.y = b;
  return r;
}

// 8-term batched reciprocal sum via PACKED f32 (v_pk_fma_f32/v_pk_mul_f32):
// sum_{k=0..7} w[k]/(1+s[k]*v[k]). Packed lanes = (h, h+1) pairs, so every
// v2f operand is an ADJACENT slice of the already-loaded float4s.
// 13 pk + 2 rcp + 2 scalar fma per 8 elems (vs 26 scalar + 2 rcp).
__device__ __forceinline__ float g4pk8(float4 s0, float4 s1, float4 w0,
                                       float4 w1, float4 v0, float4 v1,
                                       float acc) {
  const v2f one = {1.f, 1.f};
  v2f s01 = mkv2(s0.x, s0.y), s23 = mkv2(s0.z, s0.w);
  v2f s45 = mkv2(s1.x, s1.y), s67 = mkv2(s1.z, s1.w);
  v2f w01 = mkv2(w0.x, w0.y), w23 = mkv2(w0.z, w0.w);
  v2f w45 = mkv2(w1.x, w1.y), w67 = mkv2(w1.z, w1.w);
  v2f v01 = mkv2(v0.x, v0.y), v23 = mkv2(v0.z, v0.w);
  v2f v45 = mkv2(v1.x, v1.y), v67 = mkv2(v1.z, v1.w);
  v2f x01 = __builtin_elementwise_fma(s01, v01, one);
  v2f x23 = __builtin_elementwise_fma(s23, v23, one);
  v2f x45 = __builtin_elementwise_fma(s45, v45, one);
  v2f x67 = __builtin_elementwise_fma(s67, v67, one);
  v2f p03 = x01 * x23;
  v2f p47 = x45 * x67;
  v2f n03 = __builtin_elementwise_fma(w23, x01, w01 * x23);
  v2f n47 = __builtin_elementwise_fma(w67, x45, w45 * x67);
  v2f num = __builtin_elementwise_fma(n47, p03, n03 * p47);
  v2f den = p03 * p47;
  acc = fmaf(num.x, frcp(den.x), acc);
  acc = fmaf(num.y, frcp(den.y), acc);
  return acc;
}

// Session projection (R12/R13-proven, verbatim).
// esp4 PACKED [h/4][b][4]; plus C = sum(W3)+b3.
__global__ __launch_bounds__(256) void taa_esp(
    const float* __restrict__ sess, const float* __restrict__ W1,
    const float* __restrict__ b1, const float* __restrict__ W3,
    const float* __restrict__ b3, float* __restrict__ esp4,
    float* __restrict__ C_out) {
  int t = blockIdx.x * 256 + threadIdx.x;
  if (t < BSES * HDIM) {
    int b = t >> 7, h = t & 127;
    const float* srow = sess + b * EDIM;
    float acc = 0.f;
#pragma unroll 4
    for (int e = 0; e < EDIM; ++e)
      acc = fmaf(srow[e], W1[e * HDIM + h], acc);
    esp4[(h >> 2) * 256 + b * 4 + (h & 3)] = fexp2((acc + b1[h]) * KSCALE);
  }
  if (t == 0) {
    float s = b3[0];
    for (int i = 0; i < HDIM; ++i) s += W3[i];
    *C_out = s;
  }
}

// Score 4 targets (rows t0..t0+3 of the LDS et tile, row stride 128) for
// this lane's session. Loads identical to R13's passing score4; inner math
// is PACKED (2x g4pk8 per target instead of 4x scalar g4).
__device__ __forceinline__ void score4(
    const float* __restrict__ et, int t0, int lane,
    const float* __restrict__ esp4, const float* __restrict__ w3,
    float acc[4]) {
  const float* base = et + t0 * HDIM;
#pragma unroll 2
  for (int c = 0; c < 8; ++c) {
    float4 sp[4];
#pragma unroll
    for (int k = 0; k < 4; ++k)
      sp[k] = *(const float4*)(esp4 + ((c << 2) + k) * 256 + (lane << 2));
    float4 wq[4];
#pragma unroll
    for (int k = 0; k < 4; ++k)
      wq[k] = *(const float4*)(w3 + (c << 4) + k * 4);  // uniform
#pragma unroll
    for (int t = 0; t < 4; ++t) {
      const float* rp = base + t * HDIM + (c << 4);
      float4 v0 = *(const float4*)(rp + 0);  // ds_read_b128 broadcast
      float4 v1 = *(const float4*)(rp + 4);
      float4 v2 = *(const float4*)(rp + 8);
      float4 v3 = *(const float4*)(rp + 12);
      acc[t] = g4pk8(sp[0], sp[1], wq[0], wq[1], v0, v1, acc[t]);
      acc[t] = g4pk8(sp[2], sp[3], wq[2], wq[3], v2, v3, acc[t]);
    }
  }
}

// Fused per 32-target tile, 256 threads (R13-proven structure, verbatim
// except packed score4). P1: emb tile -> LDS. P2: GEMM + exp2 ->
// et[32][128] LDS. P3: score4 x2 (rows wv*4 and wv*4+16).
// score[b][n] = C - 2 * sum_h w3[h] * rcp(fma(esp[b][h], etp[n][h], 1))
__global__ __launch_bounds__(256) void taa_fused(
    const float* __restrict__ emb, const float* __restrict__ W2,
    const float* __restrict__ b2, const float* __restrict__ esp4,
    const float* __restrict__ w3, const float* __restrict__ Cptr,
    float* __restrict__ out, int N) {
  __shared__ float sm[32][132];       // emb tile, padded stride
  __shared__ float et[32 * HDIM];     // exp2(tp') tile
  const int nb = blockIdx.x * 32;

  // Phase 1: stage emb tile (coalesced float4).
  for (int k = threadIdx.x; k < 32 * 32; k += 256) {
    int r = k >> 5, c4 = k & 31;
    float4 v = make_float4(0.f, 0.f, 0.f, 0.f);
    if (nb + r < N) v = ((const float4*)(emb + (size_t)(nb + r) * EDIM))[c4];
    *(float4*)&sm[r][c4 * 4] = v;
  }
  __syncthreads();

  // Phase 2: GEMM + exp2 -> et (LDS). Thread = 4 rows x 4 h.
  {
    const int h4 = (threadIdx.x & 31) * 4;
    const int rg = threadIdx.x >> 5;  // 8 groups of 4 rows
    float acc[4][4];
#pragma unroll
    for (int j = 0; j < 4; ++j)
#pragma unroll
      for (int q = 0; q < 4; ++q) acc[j][q] = 0.f;
    for (int e = 0; e < EDIM; e += 4) {
      float4 w[4];
#pragma unroll
      for (int q = 0; q < 4; ++q)
        w[q] = *(const float4*)(W2 + (size_t)(e + q) * HDIM + h4);
#pragma unroll
      for (int j = 0; j < 4; ++j) {
        float4 em = *(const float4*)&sm[rg * 4 + j][e];
        acc[j][0] = fmaf(em.x, w[0].x, acc[j][0]);
        acc[j][1] = fmaf(em.x, w[0].y, acc[j][1]);
        acc[j][2] = fmaf(em.x, w[0].z, acc[j][2]);
        acc[j][3] = fmaf(em.x, w[0].w, acc[j][3]);
        acc[j][0] = fmaf(em.y, w[1].x, acc[j][0]);
        acc[j][1] = fmaf(em.y, w[1].y, acc[j][1]);
        acc[j][2] = fmaf(em.y, w[1].z, acc[j][2]);
        acc[j][3] = fmaf(em.y, w[1].w, acc[j][3]);
        acc[j][0] = fmaf(em.z, w[2].x, acc[j][0]);
        acc[j][1] = fmaf(em.z, w[2].y, acc[j][1]);
        acc[j][2] = fmaf(em.z, w[2].z, acc[j][2]);
        acc[j][3] = fmaf(em.z, w[2].w, acc[j][3]);
        acc[j][0] = fmaf(em.w, w[3].x, acc[j][0]);
        acc[j][1] = fmaf(em.w, w[3].y, acc[j][1]);
        acc[j][2] = fmaf(em.w, w[3].z, acc[j][2]);
        acc[j][3] = fmaf(em.w, w[3].w, acc[j][3]);
      }
    }
    float4 bb2 = *(const float4*)(b2 + h4);
#pragma unroll
    for (int j = 0; j < 4; ++j) {
      int nr = rg * 4 + j;
      float4 o;
      o.x = fexp2((acc[j][0] + bb2.x) * KSCALE);
      o.y = fexp2((acc[j][1] + bb2.y) * KSCALE);
      o.z = fexp2((acc[j][2] + bb2.z) * KSCALE);
      o.w = fexp2((acc[j][3] + bb2.w) * KSCALE);
      *(float4*)&et[nr * HDIM + h4] = o;  // wave-contiguous, conflict-free
    }
  }
  __syncthreads();

  // Phase 3: scoring. lane = session.
  const int lane = threadIdx.x & 63;
  const int wv = threadIdx.x >> 6;  // 0..3
  float acc0[4] = {0.f, 0.f, 0.f, 0.f};
  float acc1[4] = {0.f, 0.f, 0.f, 0.f};
  score4(et, wv * 4, lane, esp4, w3, acc0);
  score4(et, wv * 4 + 16, lane, esp4, w3, acc1);

  const float Cv = *Cptr;  // uniform
  const int n0 = nb + wv * 4;
  const int n1 = n0 + 16;
  float4 res0, res1;
  res0.x = fmaf(-2.f, acc0[0], Cv);
  res0.y = fmaf(-2.f, acc0[1], Cv);
  res0.z = fmaf(-2.f, acc0[2], Cv);
  res0.w = fmaf(-2.f, acc0[3], Cv);
  res1.x = fmaf(-2.f, acc1[0], Cv);
  res1.y = fmaf(-2.f, acc1[1], Cv);
  res1.z = fmaf(-2.f, acc1[2], Cv);
  res1.w = fmaf(-2.f, acc1[3], Cv);
  float* po = out + (size_t)lane * N;
  if (n0 + 3 < N) {
    *(float4*)(po + n0) = res0;
  } else {
    float r4[4] = {res0.x, res0.y, res0.z, res0.w};
    for (int i = 0; i < 4 && n0 + i < N; ++i) po[n0 + i] = r4[i];
  }
  if (n1 + 3 < N) {
    *(float4*)(po + n1) = res1;
  } else {
    float r4[4] = {res1.x, res1.y, res1.z, res1.w};
    for (int i = 0; i < 4 && n1 + i < N; ++i) po[n1 + i] = r4[i];
  }
}

extern "C" void kernel_launch(void* const* d_in, const int* in_sizes, int n_in,
                              void* d_out, int out_size, void* d_ws, size_t ws_size,
                              hipStream_t stream) {
  const float* sess = (const float*)d_in[0];
  const float* emb  = (const float*)d_in[1];
  const float* W1   = (const float*)d_in[2];
  const float* b1   = (const float*)d_in[3];
  const float* W2   = (const float*)d_in[4];
  const float* b2   = (const float*)d_in[5];
  const float* W3   = (const float*)d_in[6];
  const float* b3   = (const float*)d_in[7];
  float* out = (float*)d_out;
  const int B = in_sizes[0] / EDIM;   // 64
  const int N = in_sizes[1] / EDIM;   // 20000

  float* esp4 = (float*)d_ws;                     // B*128 floats (packed)
  float* Cp   = esp4 + (size_t)BSES * HDIM;       // 1 float

  taa_esp<<<(B * HDIM + 255) / 256, 256, 0, stream>>>(sess, W1, b1, W3, b3,
                                                      esp4, Cp);
  taa_fused<<<(N + 31) / 32, 256, 0, stream>>>(emb, W2, b2, esp4, W3, Cp,
                                               out, N);
}